// Round 15
// baseline (78.833 us; speedup 1.0000x reference)
//
#include <hip/hip_runtime.h>

#define B_    8
#define C_    64
#define O_    64
#define H_    128
#define W_    128
#define HW_   (H_ * W_)
#define NOFF_ 18
#define KK_   9

typedef __attribute__((ext_vector_type(8))) _Float16 f16x8;
typedef __attribute__((ext_vector_type(2))) _Float16 f16x2;
typedef __attribute__((ext_vector_type(4))) unsigned int u32x4;
typedef __attribute__((ext_vector_type(4))) float f32x4;
typedef unsigned int uint32;
typedef unsigned short ushort;

__device__ __forceinline__ f16x2 u2h(uint32 u) {
    union { uint32 u; f16x2 h; } c; c.u = u; return c.h;
}
__device__ __forceinline__ f16x8 u2h8(u32x4 q) {
    union { u32x4 u; f16x8 h; } c; c.u = q; return c.h;
}

#define GLOAD16(dst, a64) \
    asm volatile("global_load_dwordx4 %0, %1, off" : "=&v"(dst) : "v"(a64) : "memory")
#define WAITV(N) do { \
    asm volatile("s_waitcnt vmcnt(" #N ")" ::: "memory"); \
    __builtin_amdgcn_sched_barrier(0); } while (0)
#define DRAIN_ALL() do { \
    asm volatile("s_waitcnt vmcnt(0) lgkmcnt(0)" ::: "memory"); \
    __builtin_amdgcn_sched_barrier(0); } while (0)

// ---------------------------------------------------------------------------
// x [b][c][hw] f32  ->  xT [b][hw][c] f16   (LDS tile transpose)
// ---------------------------------------------------------------------------
__global__ __launch_bounds__(256) void transpose_x(
    const float* __restrict__ x, _Float16* __restrict__ xT)
{
    __shared__ float tile[64][65];
    int blk = blockIdx.x;
    int b   = blk >> 8;
    int hw0 = (blk & 255) * 64;
    int t   = threadIdx.x;
    int q   = t >> 6;
    int ln  = t & 63;
#pragma unroll
    for (int p = 0; p < 16; ++p) {
        int c = p * 4 + q;
        tile[c][ln] = x[((size_t)(b * C_ + c) << 14) + hw0 + ln];
    }
    __syncthreads();
#pragma unroll
    for (int p = 0; p < 16; ++p) {
        int hw = p * 4 + q;
        xT[(((size_t)b << 14) + hw0 + hw) * 64 + ln] = (_Float16)tile[ln][hw];
    }
}

// ---------------------------------------------------------------------------
// Weight fragments (f16).
// ---------------------------------------------------------------------------
__global__ __launch_bounds__(256) void prep3(
    const float* __restrict__ w_conv, const float* __restrict__ w_off,
    _Float16* __restrict__ wfrag, _Float16* __restrict__ wofff)
{
    int idx = blockIdx.x * 256 + threadIdx.x;
    if (idx < 36864) {
        int i    = idx & 7;
        int lane = (idx >> 3) & 63;
        int nb   = (idx >> 9) & 3;
        int kc   = (idx >> 11) & 1;
        int kk   = idx >> 12;
        int c = kc * 32 + ((lane >> 4) << 3) + i;
        int o = nb * 16 + (lane & 15);
        wfrag[idx] = (_Float16)w_conv[(o * C_ + c) * 9 + kk];
    }
    if (idx < 18432) {
        int i    = idx & 7;
        int lane = (idx >> 3) & 63;
        int nb   = (idx >> 9) & 1;
        int kc   = (idx >> 10) & 1;
        int kk   = idx >> 11;
        int m = nb * 16 + (lane & 15);
        int c = kc * 32 + ((lane >> 4) << 3) + i;
        wofff[idx] = (_Float16)((m < NOFF_) ? w_off[(m * C_ + c) * 9 + kk] : 0.0f);
    }
}

// ---------------------------------------------------------------------------
// Offset conv (R7-proven, unchanged).
// ---------------------------------------------------------------------------
__global__ __launch_bounds__(512, 2) void offconv_mfma5(
    const _Float16* __restrict__ xT, const _Float16* __restrict__ wofff,
    const float* __restrict__ b_off, _Float16* __restrict__ offsh)
{
    __shared__ _Float16 wlds[18432];
    int t = threadIdx.x;
    {
        const u32x4* src = (const u32x4*)wofff;
        u32x4* dst = (u32x4*)wlds;
#pragma unroll
        for (int r = 0; r < 5; ++r) {
            int i = r * 512 + t;
            if (i < 2304) dst[i] = src[i];
        }
    }
    DRAIN_ALL();
    __syncthreads();

    int blk  = blockIdx.x;
    int b    = blk & 7;
    int hw0  = (blk >> 3) * 128;
    int lane = t & 63;
    int wv   = t >> 6;
    int pxb  = hw0 + wv * 16;
    int pr   = lane & 15;
    int g    = lane >> 4;
    int px   = pxb + pr;
    int h = px >> 7, w = px & (W_ - 1);
    const _Float16* xb = xT + (((size_t)b << 14) << 6);

    f32x4 acc[2];
#pragma unroll
    for (int nb = 0; nb < 2; ++nb) acc[nb] = (f32x4){0.f, 0.f, 0.f, 0.f};

    u32x4 q[3][2];
    bool  vld[3];

    auto issueO = [&](int kk, int st) {
        int ky = kk / 3, kx = kk % 3;
        int yy = h - 1 + ky, xx = w - 1 + kx;
        vld[st] = ((unsigned)yy < (unsigned)H_) && ((unsigned)xx < (unsigned)W_);
        int src = (min(max(yy, 0), H_ - 1) << 7) + min(max(xx, 0), W_ - 1);
        unsigned long long a = (unsigned long long)(xb + ((size_t)src << 6) + g * 8);
        GLOAD16(q[st][0], a);
        unsigned long long a2 = a + 64;
        GLOAD16(q[st][1], a2);
    };

    issueO(0, 0); issueO(1, 1); issueO(2, 2);
#pragma unroll
    for (int kk = 0; kk < KK_; ++kk) {
        const int s = kk % 3;
        if (kk < 7)      { WAITV(4); }
        else if (kk < 8) { WAITV(2); }
        else             { WAITV(0); }
#pragma unroll
        for (int kc = 0; kc < 2; ++kc) {
            f16x8 a = u2h8(q[s][kc]);
            f16x8 z = {};
            a = vld[s] ? a : z;
#pragma unroll
            for (int nb = 0; nb < 2; ++nb) {
                f16x8 bfr = *(const f16x8*)(wlds +
                    ((((kk * 2 + kc) << 1) + nb) << 9) + (lane << 3));
                acc[nb] = __builtin_amdgcn_mfma_f32_16x16x32_f16(a, bfr, acc[nb], 0, 0, 0);
            }
        }
        if (kk < 6) issueO(kk + 3, s);
    }

#pragma unroll
    for (int nb = 0; nb < 2; ++nb) {
        int m = nb * 16 + pr;
        if (m < NOFF_) {
            float bias = b_off[m];
#pragma unroll
            for (int r = 0; r < 4; ++r) {
                int prow = pxb + g * 4 + r;
                offsh[(size_t)((b << 14) + prow) * NOFF_ + m] = (_Float16)(acc[nb][r] + bias);
            }
        }
    }
}

// ---------------------------------------------------------------------------
// Deformable conv R15: COALESCED gathers (R8 addressing) + HIGH OCCUPANCY.
// No x-tile, no weight LDS, no inline asm, no barriers: only the 8 KB
// wave-private swizzled bounce (0 conflicts, R8-proven). Plain loads; latency
// hidden by TLP (low VGPR -> many waves/CU), scheduling left to compiler.
// ---------------------------------------------------------------------------
__global__ __launch_bounds__(256) void deform_mfma15(
    const _Float16* __restrict__ xT, const _Float16* __restrict__ offsh,
    const _Float16* __restrict__ wfrag, float* __restrict__ out)
{
    __shared__ _Float16 val[4][1024];         // 8 KB bounce, wave-private slots

    int t    = threadIdx.x;
    int blk  = blockIdx.x;
    int b    = blk & 7;                       // XCD-aligned batch
    int hw0  = (blk >> 3) * 64;
    int lane = t & 63;
    int wv   = t >> 6;
    int pxb  = hw0 + wv * 16;
    int pr   = lane & 15;                     // fragment role: pixel row
    int gg   = lane >> 4;                     // fragment role: k-group
    int gp   = lane >> 3;                     // gather role: pixel-in-half 0..7
    int cg   = lane & 7;                      // gather role: 16B chunk 0..7
    const _Float16* xb = xT + (((size_t)b << 14) << 6);

    // offsets for this lane's fragment pixel
    const uint32* obu = (const uint32*)(offsh + (size_t)((b << 14) + pxb + pr) * NOFF_);
    uint32 dpk[9];
#pragma unroll
    for (int kk = 0; kk < 9; ++kk) dpk[kk] = obu[kk];

    f32x4 acc[4];
#pragma unroll
    for (int nb = 0; nb < 4; ++nb) acc[nb] = (f32x4){0.f, 0.f, 0.f, 0.f};

    char* mv = (char*)val[wv];                // wave-private 2KB slot

#pragma unroll
    for (int kk = 0; kk < KK_; ++kk) {
        const int ky = kk / 3, kx = kk % 3;
        u32x4 q[8];                           // [h2*4 + corner]
        f16x2 Wc[2][4];

        // ---- coalesced corner loads: 8 lanes cover one px's 128B line ----
#pragma unroll
        for (int h2 = 0; h2 < 2; ++h2) {
            int p = pxb + h2 * 8 + gp;
            uint32 du = __shfl(dpk[kk], h2 * 8 + gp, 64);
            union { uint32 u; f16x2 hh; } cv; cv.u = du;
            float dyv = (float)cv.hh[0], dxv = (float)cv.hh[1];
            int hp = p >> 7, wp = p & (W_ - 1);
            float py  = (float)(hp - 1 + ky) + dyv;
            float pxf = (float)(wp - 1 + kx) + dxv;
            float y0f = floorf(py), x0f = floorf(pxf);
            float ly = py - y0f, lx = pxf - x0f;
            int y0 = (int)y0f, x0 = (int)x0f;
            float w00 = (1.f - ly) * (1.f - lx);
            float w01 = (1.f - ly) * lx;
            float w10 = ly * (1.f - lx);
            float w11 = ly * lx;
            bool vy0 = (unsigned)y0       < (unsigned)H_;
            bool vy1 = (unsigned)(y0 + 1) < (unsigned)H_;
            bool vx0 = (unsigned)x0       < (unsigned)W_;
            bool vx1 = (unsigned)(x0 + 1) < (unsigned)W_;
            if (!(vy0 && vx0)) w00 = 0.f;
            if (!(vy0 && vx1)) w01 = 0.f;
            if (!(vy1 && vx0)) w10 = 0.f;
            if (!(vy1 && vx1)) w11 = 0.f;
            int yc0 = min(max(y0, 0), H_ - 1);
            int yc1 = min(max(y0 + 1, 0), H_ - 1);
            int xc0 = min(max(x0, 0), W_ - 1);
            int xc1 = min(max(x0 + 1, 0), W_ - 1);
            Wc[h2][0] = (f16x2){(_Float16)w00, (_Float16)w00};
            Wc[h2][1] = (f16x2){(_Float16)w01, (_Float16)w01};
            Wc[h2][2] = (f16x2){(_Float16)w10, (_Float16)w10};
            Wc[h2][3] = (f16x2){(_Float16)w11, (_Float16)w11};
            const _Float16* base = xb + cg * 8;
            q[h2 * 4 + 0] = *(const u32x4*)(base + ((size_t)((yc0 << 7) + xc0) << 6));
            q[h2 * 4 + 1] = *(const u32x4*)(base + ((size_t)((yc0 << 7) + xc1) << 6));
            q[h2 * 4 + 2] = *(const u32x4*)(base + ((size_t)((yc1 << 7) + xc0) << 6));
            q[h2 * 4 + 3] = *(const u32x4*)(base + ((size_t)((yc1 << 7) + xc1) << 6));
        }

        // ---- weights for this kk (coalesced 1KB loads, L2-hot) ----
        u32x4 wq[8];
#pragma unroll
        for (int f = 0; f < 8; ++f) {         // f = kc*4 + nb
            wq[f] = *(const u32x4*)(wfrag +
                ((((kk * 2 + (f >> 2)) << 2) + (f & 3)) << 9) + (lane << 3));
        }

        // ---- bilerp both pixel-halves in-lane, write swizzled bounce ----
#pragma unroll
        for (int h2 = 0; h2 < 2; ++h2) {
            f16x8 r;
            f16x2* rp = (f16x2*)&r;
#pragma unroll
            for (int p4 = 0; p4 < 4; ++p4) {
                rp[p4] = u2h(q[h2 * 4 + 0][p4]) * Wc[h2][0]
                       + u2h(q[h2 * 4 + 1][p4]) * Wc[h2][1]
                       + u2h(q[h2 * 4 + 2][p4]) * Wc[h2][2]
                       + u2h(q[h2 * 4 + 3][p4]) * Wc[h2][3];
            }
            int pxw = h2 * 8 + gp;
            int wb  = (pxw << 7) + (cg << 4);
            *(f16x8*)(mv + (wb ^ ((pxw & 7) << 4))) = r;
        }

        // read A-fragments (same wave; compiler inserts lgkmcnt wait)
        f16x8 a0 = *(const f16x8*)(mv + (((pr << 7) + (gg << 4))      ^ ((pr & 7) << 4)));
        f16x8 a1 = *(const f16x8*)(mv + (((pr << 7) + 64 + (gg << 4)) ^ ((pr & 7) << 4)));

#pragma unroll
        for (int nb = 0; nb < 4; ++nb)
            acc[nb] = __builtin_amdgcn_mfma_f32_16x16x32_f16(a0, u2h8(wq[nb]), acc[nb], 0, 0, 0);
#pragma unroll
        for (int nb = 0; nb < 4; ++nb)
            acc[nb] = __builtin_amdgcn_mfma_f32_16x16x32_f16(a1, u2h8(wq[4 + nb]), acc[nb], 0, 0, 0);
    }

    // C/D: col=lane&15 -> o, row=(lane>>4)*4+r -> px ; 16B vector stores
#pragma unroll
    for (int nb = 0; nb < 4; ++nb) {
        int o = nb * 16 + pr;
        float* outp = out + (((size_t)(b * O_ + o)) << 14) + pxb + (gg << 2);
        *(f32x4*)outp = acc[nb];
    }
}

// ===========================================================================
extern "C" void kernel_launch(void* const* d_in, const int* in_sizes, int n_in,
                              void* d_out, int out_size, void* d_ws, size_t ws_size,
                              hipStream_t stream)
{
    const float* x      = (const float*)d_in[0];
    const float* w_off  = (const float*)d_in[1];
    const float* b_off  = (const float*)d_in[2];
    const float* w_conv = (const float*)d_in[3];
    float* out = (float*)d_out;
    char* ws = (char*)d_ws;

    // workspace layout (bytes) — total 21,643,264
    const size_t XT_OFF    = 0;           // 16,777,216  f16 NHWC x
    const size_t OFFS_OFF  = 16777216;    //  4,718,592  f16 NHWC offsets
    const size_t WFRAG_OFF = 21495808;    //     73,728  deform weight frags
    const size_t WOFF_OFF  = 21569536;    //     36,864  offset weight frags

    _Float16* xT    = (_Float16*)(ws + XT_OFF);
    _Float16* offsh = (_Float16*)(ws + OFFS_OFF);
    _Float16* wfrag = (_Float16*)(ws + WFRAG_OFF);
    _Float16* wofff = (_Float16*)(ws + WOFF_OFF);

    transpose_x  <<<2048, 256, 0, stream>>>(x, xT);
    prep3        <<<144, 256, 0, stream>>>(w_conv, w_off, wfrag, wofff);
    offconv_mfma5<<<1024, 512, 0, stream>>>(xT, wofff, b_off, offsh);
    deform_mfma15<<<2048, 256, 0, stream>>>(xT, offsh, wfrag, out);
}

// Round 16
// 72.000 us; speedup vs baseline: 1.0949x; 1.0949x over previous
//
#include <hip/hip_runtime.h>

#define B_    8
#define C_    64
#define O_    64
#define H_    128
#define W_    128
#define HW_   (H_ * W_)
#define NOFF_ 18
#define KK_   9
#define TW_   19       // staged tile span (8 + 2*5 + 1)
#define PADW_ 5
#define RSTR_ 144      // LDS row stride in bytes

typedef __attribute__((ext_vector_type(8))) _Float16 f16x8;
typedef __attribute__((ext_vector_type(2))) _Float16 f16x2;
typedef __attribute__((ext_vector_type(4))) unsigned int u32x4;
typedef __attribute__((ext_vector_type(4))) float f32x4;
typedef unsigned int uint32;
typedef unsigned short ushort;

__device__ __forceinline__ f16x2 u2h(uint32 u) {
    union { uint32 u; f16x2 h; } c; c.u = u; return c.h;
}
__device__ __forceinline__ f16x8 u2h8(u32x4 q) {
    union { u32x4 u; f16x8 h; } c; c.u = q; return c.h;
}

#define GLOAD16(dst, a64) \
    asm volatile("global_load_dwordx4 %0, %1, off" : "=&v"(dst) : "v"(a64) : "memory")
#define WAITV_TIE(N, w) \
    asm volatile("s_waitcnt vmcnt(" #N ")" \
        : "+v"(w[0]), "+v"(w[1]), "+v"(w[2]), "+v"(w[3]), \
          "+v"(w[4]), "+v"(w[5]), "+v"(w[6]), "+v"(w[7]))
#define WAITV_TIE4(N, w) \
    asm volatile("s_waitcnt vmcnt(" #N ")" \
        : "+v"(w[0]), "+v"(w[1]), "+v"(w[2]), "+v"(w[3]))
#define WAITV(N) do { \
    asm volatile("s_waitcnt vmcnt(" #N ")" ::: "memory"); \
    __builtin_amdgcn_sched_barrier(0); } while (0)
#define WAITLGKM0() do { \
    asm volatile("s_waitcnt lgkmcnt(0)" ::: "memory"); \
    __builtin_amdgcn_sched_barrier(0); } while (0)
#define DRAIN_ALL() do { \
    asm volatile("s_waitcnt vmcnt(0) lgkmcnt(0)" ::: "memory"); \
    __builtin_amdgcn_sched_barrier(0); } while (0)

// ---------------------------------------------------------------------------
// x [b][c][hw] f32  ->  xT [b][hw][c] f16   (LDS tile transpose)
// ---------------------------------------------------------------------------
__global__ __launch_bounds__(256) void transpose_x(
    const float* __restrict__ x, _Float16* __restrict__ xT)
{
    __shared__ float tile[64][65];
    int blk = blockIdx.x;
    int b   = blk >> 8;
    int hw0 = (blk & 255) * 64;
    int t   = threadIdx.x;
    int q   = t >> 6;
    int ln  = t & 63;
#pragma unroll
    for (int p = 0; p < 16; ++p) {
        int c = p * 4 + q;
        tile[c][ln] = x[((size_t)(b * C_ + c) << 14) + hw0 + ln];
    }
    __syncthreads();
#pragma unroll
    for (int p = 0; p < 16; ++p) {
        int hw = p * 4 + q;
        xT[(((size_t)b << 14) + hw0 + hw) * 64 + ln] = (_Float16)tile[ln][hw];
    }
}

// ---------------------------------------------------------------------------
// Weight fragments (f16).
// wfrag[kk][kc][nb4][lane][i] <- w_conv ; wofff[kk][kc][nb2][lane][i] <- w_off
// ---------------------------------------------------------------------------
__global__ __launch_bounds__(256) void prep3(
    const float* __restrict__ w_conv, const float* __restrict__ w_off,
    _Float16* __restrict__ wfrag, _Float16* __restrict__ wofff)
{
    int idx = blockIdx.x * 256 + threadIdx.x;
    if (idx < 36864) {
        int i    = idx & 7;
        int lane = (idx >> 3) & 63;
        int nb   = (idx >> 9) & 3;
        int kc   = (idx >> 11) & 1;
        int kk   = idx >> 12;
        int c = kc * 32 + ((lane >> 4) << 3) + i;
        int o = nb * 16 + (lane & 15);
        wfrag[idx] = (_Float16)w_conv[(o * C_ + c) * 9 + kk];
    }
    if (idx < 18432) {
        int i    = idx & 7;
        int lane = (idx >> 3) & 63;
        int nb   = (idx >> 9) & 1;
        int kc   = (idx >> 10) & 1;
        int kk   = idx >> 11;
        int m = nb * 16 + (lane & 15);
        int c = kc * 32 + ((lane >> 4) << 3) + i;
        wofff[idx] = (_Float16)((m < NOFF_) ? w_off[(m * C_ + c) * 9 + kk] : 0.0f);
    }
}

// ---------------------------------------------------------------------------
// R16 FUSED kernel: offset-conv (phase A) + deformable conv (phase B), one
// 19x19 x-tile staged once. Phase A: integer taps from tile (zero-masked at
// image edges = zero-pad semantics), wofff streamed 2-deep (tied vmcnt(4)),
// offsets -> wave-private LDS (f32) -> registers. Phase B: R12-proven
// branch-free pipeline with clamped-LDS + linear fix-up.
// ---------------------------------------------------------------------------
__global__ __launch_bounds__(256, 3) void deform_fused(
    const _Float16* __restrict__ xT, const _Float16* __restrict__ wfrag,
    const _Float16* __restrict__ wofff, const float* __restrict__ b_off,
    float* __restrict__ out)
{
    __shared__ char  tilec[TW_ * TW_ * RSTR_];   // 51,984 B
    __shared__ float offl[4][16][20];            //  5,120 B (wave-private)

    int t    = threadIdx.x;
    int blk  = blockIdx.x;
    int b    = blk & 7;                       // XCD-aligned batch
    int tid  = blk >> 3;                      // 0..255 tile id
    int ty   = tid >> 4, tx = tid & 15;
    int lane = t & 63;
    int wv   = t >> 6;
    int pr   = lane & 15;                     // fragment px row (local px id)
    int gg   = lane >> 4;                     // fragment k-group
    int ry0  = ty * 8 - PADW_;
    int cx0  = tx * 8 - PADW_;
    const _Float16* xb = xT + (((size_t)b << 14) << 6);

    // per-lane biases for phase A epilogue (loaded early, drained by DRAIN)
    float bias0 = b_off[pr];                              // m = pr (<16)
    float bias1 = (pr < 2) ? b_off[16 + pr] : 0.0f;       // m = 16+pr

    // ---- stage clamped 19x19 neighborhood (coalesced, stride-144 rows) ----
#pragma unroll
    for (int it = 0; it < 12; ++it) {
        int idx = it * 256 + t;
        if (idx < TW_ * TW_ * 8) {
            int i   = idx / (TW_ * 8);
            int rem = idx - i * (TW_ * 8);
            int j   = rem >> 3, cg = rem & 7;
            int yy = min(max(ry0 + i, 0), H_ - 1);
            int xx = min(max(cx0 + j, 0), W_ - 1);
            u32x4 v = *(const u32x4*)(xb + (((size_t)((yy << 7) + xx)) << 6) + (cg << 3));
            int rl = i * TW_ + j;
            *(u32x4*)(tilec + rl * RSTR_ + (cg << 4)) = v;
        }
    }

    int h_img = ty * 8 + wv * 2 + (pr >> 3);
    int w_img = tx * 8 + (pr & 7);
    DRAIN_ALL();
    __syncthreads();

    // ================= Phase A: offset conv for this wave's 16 px ==========
    {
        f32x4 acco[2];
        acco[0] = (f32x4){0.f, 0.f, 0.f, 0.f};
        acco[1] = (f32x4){0.f, 0.f, 0.f, 0.f};

        u32x4 wqoA[4], wqoB[4];
        auto issueWO = [&](int kk, u32x4* wq) {
#pragma unroll
            for (int f = 0; f < 4; ++f) {     // f = kc*2 + nb
                unsigned long long wa = (unsigned long long)(wofff +
                    ((((kk * 2 + (f >> 1)) << 1) + (f & 1)) << 9) + (lane << 3));
                GLOAD16(wq[f], wa);
            }
        };

        issueWO(0, wqoA);
#pragma unroll
        for (int kk = 0; kk < KK_; ++kk) {
            u32x4* wcur = (kk & 1) ? wqoB : wqoA;
            u32x4* wnxt = (kk & 1) ? wqoA : wqoB;
            if (kk < 8) issueWO(kk + 1, wnxt);

            int ky = kk / 3, kx = kk % 3;
            int yy = h_img - 1 + ky, xx = w_img - 1 + kx;
            bool valid = ((unsigned)yy < (unsigned)H_) && ((unsigned)xx < (unsigned)W_);
            int rl = (yy - ry0) * TW_ + (xx - cx0);   // always in [0, TW*TW)
            u32x4 q0 = *(const u32x4*)(tilec + rl * RSTR_ + (gg << 4));
            u32x4 q1 = *(const u32x4*)(tilec + rl * RSTR_ + 64 + (gg << 4));
            f16x8 a0 = u2h8(q0), a1 = u2h8(q1);
            f16x8 z = {};
            a0 = valid ? a0 : z;
            a1 = valid ? a1 : z;

            if (kk < 8) { WAITV_TIE4(4, wcur); } else { WAITV_TIE4(0, wcur); }

            acco[0] = __builtin_amdgcn_mfma_f32_16x16x32_f16(a0, u2h8(wcur[0]), acco[0], 0, 0, 0);
            acco[1] = __builtin_amdgcn_mfma_f32_16x16x32_f16(a0, u2h8(wcur[1]), acco[1], 0, 0, 0);
            acco[0] = __builtin_amdgcn_mfma_f32_16x16x32_f16(a1, u2h8(wcur[2]), acco[0], 0, 0, 0);
            acco[1] = __builtin_amdgcn_mfma_f32_16x16x32_f16(a1, u2h8(wcur[3]), acco[1], 0, 0, 0);
        }

        // scatter offsets to wave-private LDS: C/D col=lane&15 -> m, row=gg*4+r -> px
#pragma unroll
        for (int r = 0; r < 4; ++r) {
            int pxl = gg * 4 + r;
            offl[wv][pxl][pr] = acco[0][r] + bias0;           // m = pr
            if (pr < 2) offl[wv][pxl][16 + pr] = acco[1][r] + bias1;
        }
        WAITLGKM0();   // same-wave write->read ordering (wave-private slot)
    }

    // read back own px offsets (f32 pairs)
    float dy[9], dx[9];
#pragma unroll
    for (int kk = 0; kk < 9; ++kk) {
        float2 dd = *(const float2*)&offl[wv][pr][2 * kk];
        dy[kk] = dd.x; dx[kk] = dd.y;
    }

    // ================= Phase B: deformable conv (R12-proven) ===============
    f32x4 acc[4];
#pragma unroll
    for (int nb = 0; nb < 4; ++nb) acc[nb] = (f32x4){0.f, 0.f, 0.f, 0.f};

    auto prepk = [&](int kk, f16x2* Wc, int* rlc, int* ycx) -> int {
        int ky = kk / 3, kx = kk % 3;
        float py  = (float)(h_img - 1 + ky) + dy[kk];
        float pxf = (float)(w_img - 1 + kx) + dx[kk];
        float y0f = floorf(py), x0f = floorf(pxf);
        float ly = py - y0f, lx = pxf - x0f;
        int y0 = (int)y0f, x0 = (int)x0f;
        float w00 = (1.f - ly) * (1.f - lx);
        float w01 = (1.f - ly) * lx;
        float w10 = ly * (1.f - lx);
        float w11 = ly * lx;
        bool vy0 = (unsigned)y0       < (unsigned)H_;
        bool vy1 = (unsigned)(y0 + 1) < (unsigned)H_;
        bool vx0 = (unsigned)x0       < (unsigned)W_;
        bool vx1 = (unsigned)(x0 + 1) < (unsigned)W_;
        if (!(vy0 && vx0)) w00 = 0.f;
        if (!(vy0 && vx1)) w01 = 0.f;
        if (!(vy1 && vx0)) w10 = 0.f;
        if (!(vy1 && vx1)) w11 = 0.f;
        int yc0 = min(max(y0, 0), H_ - 1);
        int yc1 = min(max(y0 + 1, 0), H_ - 1);
        int xc0 = min(max(x0, 0), W_ - 1);
        int xc1 = min(max(x0 + 1, 0), W_ - 1);
        Wc[0] = (f16x2){(_Float16)w00, (_Float16)w00};
        Wc[1] = (f16x2){(_Float16)w01, (_Float16)w01};
        Wc[2] = (f16x2){(_Float16)w10, (_Float16)w10};
        Wc[3] = (f16x2){(_Float16)w11, (_Float16)w11};
        ycx[0] = yc0; ycx[1] = yc1; ycx[2] = xc0; ycx[3] = xc1;
        int r0 = yc0 - ry0, r1 = yc1 - ry0;
        int c0 = xc0 - cx0, c1 = xc1 - cx0;
        int bad = ((unsigned)r0 >= TW_) | ((unsigned)r1 >= TW_) |
                  ((unsigned)c0 >= TW_) | ((unsigned)c1 >= TW_);
        r0 = min(max(r0, 0), TW_ - 1); r1 = min(max(r1, 0), TW_ - 1);
        c0 = min(max(c0, 0), TW_ - 1); c1 = min(max(c1, 0), TW_ - 1);
        rlc[0] = r0 * TW_ + c0; rlc[1] = r0 * TW_ + c1;
        rlc[2] = r1 * TW_ + c0; rlc[3] = r1 * TW_ + c1;
        return bad;
    };
    auto ldsRead = [&](const int* rlc, u32x4* q) {
#pragma unroll
        for (int kc = 0; kc < 2; ++kc) {
            int ch = (gg << 4) + (kc << 6);
#pragma unroll
            for (int cr = 0; cr < 4; ++cr)
                q[kc * 4 + cr] = *(const u32x4*)(tilec + rlc[cr] * RSTR_ + ch);
        }
    };
    auto issueW = [&](int kk, u32x4* wq) {
#pragma unroll
        for (int f = 0; f < 8; ++f) {
            unsigned long long wa = (unsigned long long)(wfrag +
                ((((kk * 2 + (f >> 2)) << 2) + (f & 3)) << 9) + (lane << 3));
            GLOAD16(wq[f], wa);
        }
    };
    auto bilerp = [&](const u32x4* q, const f16x2* Wc, int kc) -> f16x8 {
        f16x8 a;
        f16x2* ap = (f16x2*)&a;
#pragma unroll
        for (int p4 = 0; p4 < 4; ++p4) {
            ap[p4] = u2h(q[kc * 4 + 0][p4]) * Wc[0]
                   + u2h(q[kc * 4 + 1][p4]) * Wc[1]
                   + u2h(q[kc * 4 + 2][p4]) * Wc[2]
                   + u2h(q[kc * 4 + 3][p4]) * Wc[3];
        }
        return a;
    };

    u32x4 qA[8], qB[8], wqA[8], wqB[8];
    f16x2 WcA[4], WcB[4];
    int   rlA[4], rlB[4], ycxT[4];
    uint32 badmask = 0;

    issueW(0, wqA);
    if (prepk(0, WcA, rlA, ycxT)) badmask |= 1u;
    ldsRead(rlA, qA);

#pragma unroll
    for (int kk = 0; kk < KK_; ++kk) {
        u32x4* wcur = (kk & 1) ? wqB : wqA;
        u32x4* wnxt = (kk & 1) ? wqA : wqB;
        u32x4* qcur = (kk & 1) ? qB : qA;
        u32x4* qnxt = (kk & 1) ? qA : qB;
        f16x2* Wcur = (kk & 1) ? WcB : WcA;
        f16x2* Wnxt = (kk & 1) ? WcA : WcB;
        int*   rlnx = (kk & 1) ? rlA : rlB;

        if (kk < 8) {
            issueW(kk + 1, wnxt);
            if (prepk(kk + 1, Wnxt, rlnx, ycxT)) badmask |= (1u << (kk + 1));
            ldsRead(rlnx, qnxt);
        }

        f16x8 a0 = bilerp(qcur, Wcur, 0);
        f16x8 a1 = bilerp(qcur, Wcur, 1);

        if (kk < 8) { WAITV_TIE(8, wcur); } else { WAITV_TIE(0, wcur); }

#pragma unroll
        for (int nb = 0; nb < 4; ++nb)
            acc[nb] = __builtin_amdgcn_mfma_f32_16x16x32_f16(a0, u2h8(wcur[nb]), acc[nb], 0, 0, 0);
#pragma unroll
        for (int nb = 0; nb < 4; ++nb)
            acc[nb] = __builtin_amdgcn_mfma_f32_16x16x32_f16(a1, u2h8(wcur[4 + nb]), acc[nb], 0, 0, 0);
    }

    // ---- rare exact fix-up: acc += W * (exact - wrong), zero on good lanes --
    if (__any((int)(badmask != 0))) {
#pragma unroll 1
        for (int kk = 0; kk < KK_; ++kk) {
            int mybad = (badmask >> kk) & 1;
            if (__any(mybad)) {
                f16x2 Wc[4]; int rlc[4], ycx[4];
                prepk(kk, Wc, rlc, ycx);
                u32x4 qw[8], qr[8];
                ldsRead(rlc, qw);
#pragma unroll
                for (int kc = 0; kc < 2; ++kc) {
                    int ce = ((kc << 2) + gg) << 3;
#pragma unroll
                    for (int cr = 0; cr < 4; ++cr) {
                        int yy = ycx[cr >> 1], xx = ycx[2 + (cr & 1)];
                        unsigned long long a = (unsigned long long)(xb +
                            (((size_t)((yy << 7) + xx)) << 6) + ce);
                        GLOAD16(qr[kc * 4 + cr], a);
                    }
                }
                issueW(kk, wqA);
                WAITV(0);
#pragma unroll
                for (int kc = 0; kc < 2; ++kc) {
                    f16x8 aw = bilerp(qw, Wc, kc);
                    f16x8 ar = bilerp(qr, Wc, kc);
                    f16x8 d  = ar - aw;
                    f16x8 z  = {};
                    d = mybad ? d : z;
#pragma unroll
                    for (int nb = 0; nb < 4; ++nb)
                        acc[nb] = __builtin_amdgcn_mfma_f32_16x16x32_f16(
                            d, u2h8(wqA[kc * 4 + nb]), acc[nb], 0, 0, 0);
                }
            }
        }
    }

    // C/D: col=lane&15 -> o; row=gg*4+r -> p_local -> (row pair, col quad)
#pragma unroll
    for (int nb = 0; nb < 4; ++nb) {
        int o = nb * 16 + pr;
        int orow = ty * 8 + wv * 2 + (gg >> 1);
        int ocol = tx * 8 + ((gg & 1) << 2);
        float* outp = out + (((size_t)(b * O_ + o)) << 14) + (orow << 7) + ocol;
        *(f32x4*)outp = acc[nb];
    }
}

// ===========================================================================
extern "C" void kernel_launch(void* const* d_in, const int* in_sizes, int n_in,
                              void* d_out, int out_size, void* d_ws, size_t ws_size,
                              hipStream_t stream)
{
    const float* x      = (const float*)d_in[0];
    const float* w_off  = (const float*)d_in[1];
    const float* b_off  = (const float*)d_in[2];
    const float* w_conv = (const float*)d_in[3];
    float* out = (float*)d_out;
    char* ws = (char*)d_ws;

    // workspace layout (bytes)
    const size_t XT_OFF    = 0;           // 16,777,216  f16 NHWC x
    const size_t WFRAG_OFF = 21495808;    //     73,728  deform weight frags
    const size_t WOFF_OFF  = 21569536;    //     36,864  offset weight frags

    _Float16* xT    = (_Float16*)(ws + XT_OFF);
    _Float16* wfrag = (_Float16*)(ws + WFRAG_OFF);
    _Float16* wofff = (_Float16*)(ws + WOFF_OFF);

    transpose_x <<<2048, 256, 0, stream>>>(x, xT);
    prep3       <<<144, 256, 0, stream>>>(w_conv, w_off, wfrag, wofff);
    deform_fused<<<2048, 256, 0, stream>>>(xT, wfrag, wofff, b_off, out);
}

// Round 17
// 65.657 us; speedup vs baseline: 1.2007x; 1.0966x over previous
//
#include <hip/hip_runtime.h>

#define B_    8
#define C_    64
#define O_    64
#define H_    128
#define W_    128
#define HW_   (H_ * W_)
#define NOFF_ 18
#define KK_   9
#define TW_   19       // staged tile span (8 + 2*5 + 1)
#define PADW_ 5
#define RSTR_ 144      // LDS row stride in bytes (non-pow2)

typedef __attribute__((ext_vector_type(8))) _Float16 f16x8;
typedef __attribute__((ext_vector_type(2))) _Float16 f16x2;
typedef __attribute__((ext_vector_type(4))) unsigned int u32x4;
typedef __attribute__((ext_vector_type(4))) float f32x4;
typedef unsigned int uint32;
typedef unsigned short ushort;

__device__ __forceinline__ f16x2 u2h(uint32 u) {
    union { uint32 u; f16x2 h; } c; c.u = u; return c.h;
}
__device__ __forceinline__ f16x8 u2h8(u32x4 q) {
    union { u32x4 u; f16x8 h; } c; c.u = q; return c.h;
}

#define GLOAD16(dst, a64) \
    asm volatile("global_load_dwordx4 %0, %1, off" : "=&v"(dst) : "v"(a64) : "memory")
#define WAITV_TIE(N, w) \
    asm volatile("s_waitcnt vmcnt(" #N ")" \
        : "+v"(w[0]), "+v"(w[1]), "+v"(w[2]), "+v"(w[3]), \
          "+v"(w[4]), "+v"(w[5]), "+v"(w[6]), "+v"(w[7]))
#define WAITV(N) do { \
    asm volatile("s_waitcnt vmcnt(" #N ")" ::: "memory"); \
    __builtin_amdgcn_sched_barrier(0); } while (0)
#define DRAIN_ALL() do { \
    asm volatile("s_waitcnt vmcnt(0) lgkmcnt(0)" ::: "memory"); \
    __builtin_amdgcn_sched_barrier(0); } while (0)

// ---------------------------------------------------------------------------
// x [b][c][hw] f32  ->  xT [b][hw][c] f16   (LDS tile transpose)
// ---------------------------------------------------------------------------
__global__ __launch_bounds__(256) void transpose_x(
    const float* __restrict__ x, _Float16* __restrict__ xT)
{
    __shared__ float tile[64][65];
    int blk = blockIdx.x;
    int b   = blk >> 8;
    int hw0 = (blk & 255) * 64;
    int t   = threadIdx.x;
    int q   = t >> 6;
    int ln  = t & 63;
#pragma unroll
    for (int p = 0; p < 16; ++p) {
        int c = p * 4 + q;
        tile[c][ln] = x[((size_t)(b * C_ + c) << 14) + hw0 + ln];
    }
    __syncthreads();
#pragma unroll
    for (int p = 0; p < 16; ++p) {
        int hw = p * 4 + q;
        xT[(((size_t)b << 14) + hw0 + hw) * 64 + ln] = (_Float16)tile[ln][hw];
    }
}

// ---------------------------------------------------------------------------
// Weight fragments (f16).
// ---------------------------------------------------------------------------
__global__ __launch_bounds__(256) void prep3(
    const float* __restrict__ w_conv, const float* __restrict__ w_off,
    _Float16* __restrict__ wfrag, _Float16* __restrict__ wofff)
{
    int idx = blockIdx.x * 256 + threadIdx.x;
    if (idx < 36864) {
        int i    = idx & 7;
        int lane = (idx >> 3) & 63;
        int nb   = (idx >> 9) & 3;
        int kc   = (idx >> 11) & 1;
        int kk   = idx >> 12;
        int c = kc * 32 + ((lane >> 4) << 3) + i;
        int o = nb * 16 + (lane & 15);
        wfrag[idx] = (_Float16)w_conv[(o * C_ + c) * 9 + kk];
    }
    if (idx < 18432) {
        int i    = idx & 7;
        int lane = (idx >> 3) & 63;
        int nb   = (idx >> 9) & 1;
        int kc   = (idx >> 10) & 1;
        int kk   = idx >> 11;
        int m = nb * 16 + (lane & 15);
        int c = kc * 32 + ((lane >> 4) << 3) + i;
        wofff[idx] = (_Float16)((m < NOFF_) ? w_off[(m * C_ + c) * 9 + kk] : 0.0f);
    }
}

// ---------------------------------------------------------------------------
// Offset conv (R7-proven, unchanged).
// ---------------------------------------------------------------------------
__global__ __launch_bounds__(512, 2) void offconv_mfma5(
    const _Float16* __restrict__ xT, const _Float16* __restrict__ wofff,
    const float* __restrict__ b_off, _Float16* __restrict__ offsh)
{
    __shared__ _Float16 wlds[18432];
    int t = threadIdx.x;
    {
        const u32x4* src = (const u32x4*)wofff;
        u32x4* dst = (u32x4*)wlds;
#pragma unroll
        for (int r = 0; r < 5; ++r) {
            int i = r * 512 + t;
            if (i < 2304) dst[i] = src[i];
        }
    }
    DRAIN_ALL();
    __syncthreads();

    int blk  = blockIdx.x;
    int b    = blk & 7;
    int hw0  = (blk >> 3) * 128;
    int lane = t & 63;
    int wv   = t >> 6;
    int pxb  = hw0 + wv * 16;
    int pr   = lane & 15;
    int g    = lane >> 4;
    int px   = pxb + pr;
    int h = px >> 7, w = px & (W_ - 1);
    const _Float16* xb = xT + (((size_t)b << 14) << 6);

    f32x4 acc[2];
#pragma unroll
    for (int nb = 0; nb < 2; ++nb) acc[nb] = (f32x4){0.f, 0.f, 0.f, 0.f};

    u32x4 q[3][2];
    bool  vld[3];

    auto issueO = [&](int kk, int st) {
        int ky = kk / 3, kx = kk % 3;
        int yy = h - 1 + ky, xx = w - 1 + kx;
        vld[st] = ((unsigned)yy < (unsigned)H_) && ((unsigned)xx < (unsigned)W_);
        int src = (min(max(yy, 0), H_ - 1) << 7) + min(max(xx, 0), W_ - 1);
        unsigned long long a = (unsigned long long)(xb + ((size_t)src << 6) + g * 8);
        GLOAD16(q[st][0], a);
        unsigned long long a2 = a + 64;
        GLOAD16(q[st][1], a2);
    };

    issueO(0, 0); issueO(1, 1); issueO(2, 2);
#pragma unroll
    for (int kk = 0; kk < KK_; ++kk) {
        const int s = kk % 3;
        if (kk < 7)      { WAITV(4); }
        else if (kk < 8) { WAITV(2); }
        else             { WAITV(0); }
#pragma unroll
        for (int kc = 0; kc < 2; ++kc) {
            f16x8 a = u2h8(q[s][kc]);
            f16x8 z = {};
            a = vld[s] ? a : z;
#pragma unroll
            for (int nb = 0; nb < 2; ++nb) {
                f16x8 bfr = *(const f16x8*)(wlds +
                    ((((kk * 2 + kc) << 1) + nb) << 9) + (lane << 3));
                acc[nb] = __builtin_amdgcn_mfma_f32_16x16x32_f16(a, bfr, acc[nb], 0, 0, 0);
            }
        }
        if (kk < 6) issueO(kk + 3, s);
    }

#pragma unroll
    for (int nb = 0; nb < 2; ++nb) {
        int m = nb * 16 + pr;
        if (m < NOFF_) {
            float bias = b_off[m];
#pragma unroll
            for (int r = 0; r < 4; ++r) {
                int prow = pxb + g * 4 + r;
                offsh[(size_t)((b << 14) + prow) * NOFF_ + m] = (_Float16)(acc[nb][r] + bias);
            }
        }
    }
}

// ---------------------------------------------------------------------------
// Deformable conv (R12-proven, best known): 8x8 px/block, 19x19 LDS x-tile
// (stride-144 rows), weight double-buffer with tie-waited vmcnt(8), per-kk
// window check with rare global-gather fallback.
// ---------------------------------------------------------------------------
__global__ __launch_bounds__(256, 3) void deform_mfma10(
    const _Float16* __restrict__ xT, const _Float16* __restrict__ offsh,
    const _Float16* __restrict__ wfrag, float* __restrict__ out)
{
    __shared__ char tilec[TW_ * TW_ * RSTR_];   // 51,984 B

    int t    = threadIdx.x;
    int blk  = blockIdx.x;
    int b    = blk & 7;                       // XCD-aligned batch
    int tid  = blk >> 3;                      // 0..255 tile id
    int ty   = tid >> 4, tx = tid & 15;
    int lane = t & 63;
    int wv   = t >> 6;
    int pr   = lane & 15;                     // fragment px row
    int gg   = lane >> 4;                     // fragment k-group
    int ry0  = ty * 8 - PADW_;
    int cx0  = tx * 8 - PADW_;
    const _Float16* xb = xT + (((size_t)b << 14) << 6);

    // ---- stage clamped 19x19 neighborhood (coalesced, stride-144 rows) ----
#pragma unroll
    for (int it = 0; it < 12; ++it) {
        int idx = it * 256 + t;
        if (idx < TW_ * TW_ * 8) {
            int i   = idx / (TW_ * 8);
            int rem = idx - i * (TW_ * 8);
            int j   = rem >> 3, cg = rem & 7;
            int yy = min(max(ry0 + i, 0), H_ - 1);
            int xx = min(max(cx0 + j, 0), W_ - 1);
            u32x4 v = *(const u32x4*)(xb + (((size_t)((yy << 7) + xx)) << 6) + (cg << 3));
            int rl = i * TW_ + j;
            *(u32x4*)(tilec + rl * RSTR_ + (cg << 4)) = v;
        }
    }

    // per-lane pixel (fragment role) + its 9 offset pairs
    int h_img = ty * 8 + wv * 2 + (pr >> 3);
    int w_img = tx * 8 + (pr & 7);
    const uint32* obu = (const uint32*)(offsh +
        (size_t)((b << 14) + (h_img << 7) + w_img) * NOFF_);
    uint32 dpk[9];
#pragma unroll
    for (int kk = 0; kk < 9; ++kk) dpk[kk] = obu[kk];
    DRAIN_ALL();
    __syncthreads();

    f32x4 acc[4];
#pragma unroll
    for (int nb = 0; nb < 4; ++nb) acc[nb] = (f32x4){0.f, 0.f, 0.f, 0.f};

    u32x4 wqA[8], wqB[8];   // weight double-buffer (static names, rule #20)
    u32x4 q[8];             // corner data [kc*4 + corner]

    auto issueW = [&](int kk, u32x4* wq) {
#pragma unroll
        for (int f = 0; f < 8; ++f) {         // f = kc*4 + nb
            unsigned long long wa = (unsigned long long)(wfrag +
                ((((kk * 2 + (f >> 2)) << 2) + (f & 3)) << 9) + (lane << 3));
            GLOAD16(wq[f], wa);
        }
    };

    issueW(0, wqA);
#pragma unroll
    for (int kk = 0; kk < KK_; ++kk) {
        u32x4* wcur = (kk & 1) ? wqB : wqA;
        u32x4* wnxt = (kk & 1) ? wqA : wqB;
        if (kk < 8) issueW(kk + 1, wnxt);

        // bilinear prep for this lane's own pixel (pure VALU, schedulable)
        int ky = kk / 3, kx = kk % 3;
        union { uint32 u; f16x2 hh; } cv; cv.u = dpk[kk];
        float dyv = (float)cv.hh[0], dxv = (float)cv.hh[1];
        float py  = (float)(h_img - 1 + ky) + dyv;
        float pxf = (float)(w_img - 1 + kx) + dxv;
        float y0f = floorf(py), x0f = floorf(pxf);
        float ly = py - y0f, lx = pxf - x0f;
        int y0 = (int)y0f, x0 = (int)x0f;
        float w00 = (1.f - ly) * (1.f - lx);
        float w01 = (1.f - ly) * lx;
        float w10 = ly * (1.f - lx);
        float w11 = ly * lx;
        bool vy0 = (unsigned)y0       < (unsigned)H_;
        bool vy1 = (unsigned)(y0 + 1) < (unsigned)H_;
        bool vx0 = (unsigned)x0       < (unsigned)W_;
        bool vx1 = (unsigned)(x0 + 1) < (unsigned)W_;
        if (!(vy0 && vx0)) w00 = 0.f;
        if (!(vy0 && vx1)) w01 = 0.f;
        if (!(vy1 && vx0)) w10 = 0.f;
        if (!(vy1 && vx1)) w11 = 0.f;
        int yc0 = min(max(y0, 0), H_ - 1);
        int yc1 = min(max(y0 + 1, 0), H_ - 1);
        int xc0 = min(max(x0, 0), W_ - 1);
        int xc1 = min(max(x0 + 1, 0), W_ - 1);
        f16x2 Wc0 = (f16x2){(_Float16)w00, (_Float16)w00};
        f16x2 Wc1 = (f16x2){(_Float16)w01, (_Float16)w01};
        f16x2 Wc2 = (f16x2){(_Float16)w10, (_Float16)w10};
        f16x2 Wc3 = (f16x2){(_Float16)w11, (_Float16)w11};

        int r0 = yc0 - ry0, r1 = yc1 - ry0;
        int c0 = xc0 - cx0, c1 = xc1 - cx0;
        int bad = ((unsigned)r0 >= TW_) | ((unsigned)r1 >= TW_) |
                  ((unsigned)c0 >= TW_) | ((unsigned)c1 >= TW_);

        if (!__any(bad)) {
            // LDS gather: plain loads, stride-144 rows, compiler-scheduled
            int rl00 = r0 * TW_ + c0, rl01 = r0 * TW_ + c1;
            int rl10 = r1 * TW_ + c0, rl11 = r1 * TW_ + c1;
            int ch0 = gg << 4;
#pragma unroll
            for (int kc = 0; kc < 2; ++kc) {
                int ch = ch0 + (kc << 6);
                q[kc * 4 + 0] = *(const u32x4*)(tilec + rl00 * RSTR_ + ch);
                q[kc * 4 + 1] = *(const u32x4*)(tilec + rl01 * RSTR_ + ch);
                q[kc * 4 + 2] = *(const u32x4*)(tilec + rl10 * RSTR_ + ch);
                q[kc * 4 + 3] = *(const u32x4*)(tilec + rl11 * RSTR_ + ch);
            }
        } else {
            // rare fallback: exact global gathers, full drain (sched-pinned ok)
#pragma unroll
            for (int kc = 0; kc < 2; ++kc) {
                int ce = ((kc << 2) + gg) << 3;
                unsigned long long a00 = (unsigned long long)(xb + (((size_t)((yc0 << 7) + xc0)) << 6) + ce);
                unsigned long long a01 = (unsigned long long)(xb + (((size_t)((yc0 << 7) + xc1)) << 6) + ce);
                unsigned long long a10 = (unsigned long long)(xb + (((size_t)((yc1 << 7) + xc0)) << 6) + ce);
                unsigned long long a11 = (unsigned long long)(xb + (((size_t)((yc1 << 7) + xc1)) << 6) + ce);
                GLOAD16(q[kc * 4 + 0], a00);
                GLOAD16(q[kc * 4 + 1], a01);
                GLOAD16(q[kc * 4 + 2], a10);
                GLOAD16(q[kc * 4 + 3], a11);
            }
            WAITV(0);
        }

        // wait (tied) for THIS kk's weights: kk<8 -> next-kk's 8 still inflight
        if (kk < 8) { WAITV_TIE(8, wcur); } else { WAITV_TIE(0, wcur); }

        // bilerp + MFMA
#pragma unroll
        for (int kc = 0; kc < 2; ++kc) {
            f16x8 a;
            f16x2* ap = (f16x2*)&a;
#pragma unroll
            for (int p4 = 0; p4 < 4; ++p4) {
                ap[p4] = u2h(q[kc * 4 + 0][p4]) * Wc0
                       + u2h(q[kc * 4 + 1][p4]) * Wc1
                       + u2h(q[kc * 4 + 2][p4]) * Wc2
                       + u2h(q[kc * 4 + 3][p4]) * Wc3;
            }
#pragma unroll
            for (int nb = 0; nb < 4; ++nb) {
                acc[nb] = __builtin_amdgcn_mfma_f32_16x16x32_f16(
                    a, u2h8(wcur[kc * 4 + nb]), acc[nb], 0, 0, 0);
            }
        }
    }

    // C/D: col=lane&15 -> o; row=gg*4+r -> p_local -> (row pair, col quad)
#pragma unroll
    for (int nb = 0; nb < 4; ++nb) {
        int o = nb * 16 + pr;
        int orow = ty * 8 + wv * 2 + (gg >> 1);
        int ocol = tx * 8 + ((gg & 1) << 2);
        float* outp = out + (((size_t)(b * O_ + o)) << 14) + (orow << 7) + ocol;
        *(f32x4*)outp = acc[nb];
    }
}

// ===========================================================================
extern "C" void kernel_launch(void* const* d_in, const int* in_sizes, int n_in,
                              void* d_out, int out_size, void* d_ws, size_t ws_size,
                              hipStream_t stream)
{
    const float* x      = (const float*)d_in[0];
    const float* w_off  = (const float*)d_in[1];
    const float* b_off  = (const float*)d_in[2];
    const float* w_conv = (const float*)d_in[3];
    float* out = (float*)d_out;
    char* ws = (char*)d_ws;

    // workspace layout (bytes) — total 21,643,264
    const size_t XT_OFF    = 0;           // 16,777,216  f16 NHWC x
    const size_t OFFS_OFF  = 16777216;    //  4,718,592  f16 NHWC offsets
    const size_t WFRAG_OFF = 21495808;    //     73,728  deform weight frags
    const size_t WOFF_OFF  = 21569536;    //     36,864  offset weight frags

    _Float16* xT    = (_Float16*)(ws + XT_OFF);
    _Float16* offsh = (_Float16*)(ws + OFFS_OFF);
    _Float16* wfrag = (_Float16*)(ws + WFRAG_OFF);
    _Float16* wofff = (_Float16*)(ws + WOFF_OFF);

    transpose_x  <<<2048, 256, 0, stream>>>(x, xT);
    prep3        <<<144, 256, 0, stream>>>(w_conv, w_off, wfrag, wofff);
    offconv_mfma5<<<1024, 512, 0, stream>>>(xT, wofff, b_off, offsh);
    deform_mfma10<<<2048, 256, 0, stream>>>(xT, offsh, wfrag, out);
}